// Round 16
// baseline (283.634 us; speedup 1.0000x reference)
//
#include <hip/hip_runtime.h>
#include <hip/hip_bf16.h>
#include <cstdint>

#define B_ 64
#define S_ 2048
#define D_ 512
#define H_ 512

typedef short s16x8 __attribute__((ext_vector_type(8)));
typedef float f32x4 __attribute__((ext_vector_type(4)));
typedef unsigned short u16x8 __attribute__((ext_vector_type(8)));

static __device__ __forceinline__ unsigned short f2bf(float f) {
  __bf16 h = (__bf16)f;
  return __builtin_bit_cast(unsigned short, h);
}
static __device__ __forceinline__ float bf2f(unsigned short u) {
  unsigned int w = ((unsigned int)u) << 16;
  return __builtin_bit_cast(float, w);
}

// ---------------- fused prep: detect (128 blk) + W-pack (128 blk) + inp (64 blk) ----
__global__ __launch_bounds__(256) void k_prep(
    const unsigned int* __restrict__ mw, int* __restrict__ flags,
    const float* __restrict__ W, unsigned short* __restrict__ Wp,
    const float* __restrict__ x, const float* __restrict__ W_in,
    const float* __restrict__ b_in, const float* __restrict__ b_ctx,
    float* __restrict__ inp_pb) {
  const int bx = blockIdx.x;
  const int t = threadIdx.x;
  if (bx < 128) {
    __shared__ int blk;
    if (t == 0) blk = 0;
    __syncthreads();
    unsigned w = mw[bx * 256 + t];
    int bits = 0;
    if (w == 0x3F800000u) bits = 2;
    else if (w > 1u) bits = 1;
    unsigned long long a1 = __ballot(bits & 1);
    unsigned long long a2 = __ballot(bits & 2);
    if ((t & 63) == 0) {
      int v = (a1 ? 1 : 0) | (a2 ? 2 : 0);
      if (v) atomicOr(&blk, v);
    }
    __syncthreads();
    if (t == 0) flags[bx] = blk;
  } else if (bx < 256) {
    // pack W_ctx -> fragment-major bf16:
    // Wp[((kb*32+hb)*64+lane)*8+e] = bf16(W[hb*16+(lane&15)][kb*32+(lane>>4)*8+e])
    const int tid = (bx - 128) * 256 + t;
    const int lane = tid & 63;
    const int hb = (tid >> 6) & 31;
    const int kb = tid >> 11;
    const int h = hb * 16 + (lane & 15);
    const int k = kb * 32 + (lane >> 4) * 8;
    const float* src = W + (size_t)h * D_ + k;
    float4 a = *(const float4*)src;
    float4 c = *(const float4*)(src + 4);
    s16x8 o;
    o[0] = (short)f2bf(a.x); o[1] = (short)f2bf(a.y);
    o[2] = (short)f2bf(a.z); o[3] = (short)f2bf(a.w);
    o[4] = (short)f2bf(c.x); o[5] = (short)f2bf(c.y);
    o[6] = (short)f2bf(c.z); o[7] = (short)f2bf(c.w);
    *(s16x8*)(Wp + (size_t)tid * 8) = o;
  } else {
    // inp' = x @ W_in^T + b_in + b_ctx  (one block per b)
    const int b = bx - 256;
    __shared__ float xs[D_];
    xs[t] = x[b * D_ + t];
    xs[t + 256] = x[b * D_ + t + 256];
    __syncthreads();
    for (int h = t; h < H_; h += 256) {
      const float4* wr = (const float4*)(W_in + (size_t)h * D_);
      float acc = 0.f;
#pragma unroll 4
      for (int d4 = 0; d4 < 128; ++d4) {
        float4 w = wr[d4];
        acc += w.x * xs[d4 * 4] + w.y * xs[d4 * 4 + 1] + w.z * xs[d4 * 4 + 2] +
               w.w * xs[d4 * 4 + 3];
      }
      inp_pb[b * H_ + h] = acc + b_in[h] + b_ctx[h];
    }
  }
}

// ---------------- pack context -> bf16 fragment-major ----------------
// Bp[(((b*32+st)*16+kb)*4+n)*64+lane][e] =
//   bf16(ctx[b][st*64 + n*16 + (lane&15)][kb*32 + (lane>>4)*8 + e])
// Read: each 128B line of ctx fully consumed by 4 lanes of one wave.
// Write: contiguous 1KB per wave.
__global__ __launch_bounds__(256) void k_packctx(const float* __restrict__ ctx,
                                                 unsigned short* __restrict__ Bp) {
  const int tid = blockIdx.x * 256 + threadIdx.x;  // 32768 blocks
  const int lane = tid & 63;
  const int q = tid >> 6;
  const int n = q & 3;
  const int kb = (q >> 2) & 15;
  const int st = (q >> 6) & 31;
  const int b = q >> 11;
  const int s = st * 64 + n * 16 + (lane & 15);
  const int k = kb * 32 + (lane >> 4) * 8;
  const float* src = ctx + ((size_t)b * S_ + s) * D_ + k;
  float4 a = *(const float4*)src;
  float4 c = *(const float4*)(src + 4);
  s16x8 o;
  o[0] = (short)f2bf(a.x); o[1] = (short)f2bf(a.y);
  o[2] = (short)f2bf(a.z); o[3] = (short)f2bf(a.w);
  o[4] = (short)f2bf(c.x); o[5] = (short)f2bf(c.y);
  o[6] = (short)f2bf(c.z); o[7] = (short)f2bf(c.w);
  __builtin_nontemporal_store(o, (s16x8*)(Bp + (size_t)tid * 8));
}

// ---------------- att[b,s] = sum_h V[h]*tanh(inp'[b,h] + (W_ctx@ctx^T)[h,s]) ----
// LDS-FREE, BARRIER-FREE K-loop: both operands pre-packed fragment-major in
// global (A: Wp 512KB L2-hot; B: Bp 64KB/tile, 1st wave pulls L3->L2, rest hit
// L2). Per K-step: 4 A-bursts + 4 B-bursts (contiguous 1KB/wave) + 16 MFMAs;
// compiler pipelines with counted vmcnt (no barriers to drain).
// FIX vs R15: bp base stride is 32768 shorts per (b,st) block (16kb x 4n x
// 512 shorts/fragment), not 512.
__global__ __launch_bounds__(512, 4) void k_att(
    const unsigned short* __restrict__ Bp, const unsigned short* __restrict__ Wp,
    const float* __restrict__ inp_pb, const float* __restrict__ V,
    float* __restrict__ att) {
  __shared__ float red[8][64];
  const int tid = threadIdx.x;
  const int wave = tid >> 6, lane = tid & 63;
  const int st = blockIdx.x, b = blockIdx.y;
  const int s0 = st * 64;
  const int hbase = wave * 64;
  const int blh = lane >> 4;

  const unsigned short* ap = Wp + ((size_t)(wave * 4) * 64 + lane) * 8;
  const unsigned short* bp = Bp + (size_t)(b * 32 + st) * 32768 + (size_t)lane * 8;

  f32x4 acc[4][4];
#pragma unroll
  for (int m = 0; m < 4; ++m)
#pragma unroll
    for (int n = 0; n < 4; ++n) acc[m][n] = f32x4{0.f, 0.f, 0.f, 0.f};

#pragma unroll
  for (int kb = 0; kb < 16; ++kb) {
    s16x8 af[4], bf[4];
#pragma unroll
    for (int m = 0; m < 4; ++m)
      af[m] = *(const s16x8*)(ap + (size_t)(kb * 32 + m) * 512);
#pragma unroll
    for (int n = 0; n < 4; ++n)
      bf[n] = *(const s16x8*)(bp + (size_t)(kb * 4 + n) * 512);
#pragma unroll
    for (int m = 0; m < 4; ++m)
#pragma unroll
      for (int n = 0; n < 4; ++n)
        acc[m][n] = __builtin_amdgcn_mfma_f32_16x16x32_bf16(af[m], bf[n],
                                                            acc[m][n], 0, 0, 0);
  }

  // epilogue: cheap inf-safe tanh + V-dot, reduce over h
  float attp[4] = {0.f, 0.f, 0.f, 0.f};
  const float* ib = inp_pb + b * H_;
#pragma unroll
  for (int m = 0; m < 4; ++m) {
#pragma unroll
    for (int j = 0; j < 4; ++j) {
      int h = hbase + m * 16 + (blh << 2) + j;
      float c = ib[h];
      float vh = V[h];
#pragma unroll
      for (int n = 0; n < 4; ++n) {
        float x = acc[m][n][j] + c;
        float ax = __builtin_fabsf(x);
        float e = __expf(2.f * ax);
        float tt = 1.f - 2.f * __builtin_amdgcn_rcpf(e + 1.f);
        attp[n] += vh * copysignf(tt, x);
      }
    }
  }
#pragma unroll
  for (int n = 0; n < 4; ++n) {
    attp[n] += __shfl_xor(attp[n], 16, 64);
    attp[n] += __shfl_xor(attp[n], 32, 64);
  }
  if (lane < 16) {
#pragma unroll
    for (int n = 0; n < 4; ++n) red[wave][n * 16 + lane] = attp[n];
  }
  __syncthreads();
  if (tid < 64) {
    float s = 0.f;
#pragma unroll
    for (int w = 0; w < 8; ++w) s += red[w][tid];
    att[(size_t)b * S_ + s0 + tid] = s;
  }
}

// ---------------- masked softmax over S -> alpha ----------------
__global__ void k_softmax(const float* __restrict__ att, const void* __restrict__ mask,
                          const int* __restrict__ flags, float* __restrict__ alpha) {
  const int b = blockIdx.x, t = threadIdx.x;
  __shared__ int cshared;
  __shared__ float sm[4];
  if (t < 64) {
    int v = flags[t] | flags[t + 64];
    for (int off = 32; off; off >>= 1) v |= __shfl_xor(v, off, 64);
    if (t == 0) cshared = v;
  }
  __syncthreads();
  const int c = cshared;
  const int mtype = (c & 2) ? 2 : (c & 1);  // 2=float, 1=bytes, 0=int32
  const unsigned char* m8 = (const unsigned char*)mask;
  const int* m32 = (const int*)mask;
  const float* mf = (const float*)mask;
  float vals[8];
  float mx = -3.0e38f;
#pragma unroll
  for (int i = 0; i < 8; ++i) {
    int s = t + i * 256;
    size_t idx = (size_t)b * S_ + s;
    int msk = (mtype == 1) ? (int)m8[idx] : (mtype == 2) ? (mf[idx] != 0.f) : m32[idx];
    float v = msk ? -__builtin_inff() : att[idx];
    vals[i] = v;
    mx = fmaxf(mx, v);
  }
  for (int off = 32; off; off >>= 1) mx = fmaxf(mx, __shfl_xor(mx, off, 64));
  if ((t & 63) == 0) sm[t >> 6] = mx;
  __syncthreads();
  mx = fmaxf(fmaxf(sm[0], sm[1]), fmaxf(sm[2], sm[3]));
  float es[8];
  float sum = 0.f;
#pragma unroll
  for (int i = 0; i < 8; ++i) {
    es[i] = __expf(vals[i] - mx);
    sum += es[i];
  }
  for (int off = 32; off; off >>= 1) sum += __shfl_xor(sum, off, 64);
  __syncthreads();
  if ((t & 63) == 0) sm[t >> 6] = sum;
  __syncthreads();
  sum = sm[0] + sm[1] + sm[2] + sm[3];
  float inv = __fdividef(1.f, sum);
#pragma unroll
  for (int i = 0; i < 8; ++i) alpha[(size_t)b * S_ + t + i * 256] = es[i] * inv;
}

// ---------------- y[b][d] = sum_s alpha*ctx from fragment-major Bp ----------------
// Block = (kb, b); wave w handles st in [w*8, w*8+8); lane (sl=lane&15 -> s,
// kh=lane>>4 -> k-chunk) accumulates 8 f32. LDS combine + final 32 writes.
__global__ __launch_bounds__(256) void k_ypart16f(const unsigned short* __restrict__ Bp,
                                                  const float* __restrict__ alpha,
                                                  float* __restrict__ y) {
  const int kb = blockIdx.x, b = blockIdx.y, t = threadIdx.x;
  const int wave = t >> 6, lane = t & 63;
  const int sl = lane & 15;
  __shared__ float comb[256][8];
  float a8[8];
#pragma unroll
  for (int j = 0; j < 8; ++j) a8[j] = 0.f;
  const float* al = alpha + (size_t)b * S_;
  for (int st = wave * 8; st < wave * 8 + 8; ++st) {
#pragma unroll
    for (int n = 0; n < 4; ++n) {
      const size_t fi = ((((size_t)(b * 32 + st) * 16 + kb) * 4 + n) * 64 + lane) * 8;
      u16x8 v = *(const u16x8*)(Bp + fi);
      float a = al[st * 64 + n * 16 + sl];
#pragma unroll
      for (int j = 0; j < 8; ++j) a8[j] += a * bf2f(v[j]);
    }
  }
#pragma unroll
  for (int j = 0; j < 8; ++j) comb[t][j] = a8[j];
  __syncthreads();
  if (t < 32) {
    const int kh = t >> 3, e = t & 7;
    float s = 0.f;
#pragma unroll
    for (int w = 0; w < 4; ++w)
      for (int s2 = 0; s2 < 16; ++s2) s += comb[w * 64 + kh * 16 + s2][e];
    y[(size_t)b * D_ + kb * 32 + t] = s;
  }
}

// ---------------- hidden = W_ctx @ y + b_ctx (exact f32) ----------------
__global__ void k_hidden(const float* __restrict__ y, const float* __restrict__ W_ctx,
                         const float* __restrict__ b_ctx, float* __restrict__ hidden) {
  const int b = blockIdx.x, t = threadIdx.x;
  __shared__ float ys[D_];
  for (int d = t; d < D_; d += 256) ys[d] = y[(size_t)b * D_ + d];
  __syncthreads();
  for (int h = t; h < H_; h += 256) {
    const float4* wr = (const float4*)(W_ctx + (size_t)h * D_);
    float acc = 0.f;
#pragma unroll 4
    for (int d4 = 0; d4 < 128; ++d4) {
      float4 w = wr[d4];
      acc += w.x * ys[d4 * 4] + w.y * ys[d4 * 4 + 1] + w.z * ys[d4 * 4 + 2] +
             w.w * ys[d4 * 4 + 3];
    }
    hidden[b * H_ + h] = acc + b_ctx[h];
  }
}

extern "C" void kernel_launch(void* const* d_in, const int* in_sizes, int n_in,
                              void* d_out, int out_size, void* d_ws, size_t ws_size,
                              hipStream_t stream) {
  (void)in_sizes; (void)n_in; (void)out_size; (void)ws_size;
  const float* x = (const float*)d_in[0];
  const float* context = (const float*)d_in[1];
  const void* mask = d_in[2];
  const float* W_in = (const float*)d_in[3];
  const float* b_in = (const float*)d_in[4];
  const float* W_ctx = (const float*)d_in[5];
  const float* b_ctx = (const float*)d_in[6];
  const float* V = (const float*)d_in[7];

  float* out_hidden = (float*)d_out;           // [B,H]
  float* out_alpha = (float*)d_out + B_ * H_;  // [B,S]

  // workspace: inp_pb 128K | att 512K | y 128K | flags 512B | Wp 512K | Bp 134M
  // (ws >= 136MB verified empirically in rounds 4 & 14)
  char* ws = (char*)d_ws;
  float* inp_pb = (float*)ws;                            // B*H f32
  float* att = (float*)(ws + 131072);                    // B*S f32
  float* y = (float*)(ws + 655360);                      // B*D f32
  int* flags = (int*)(ws + 786432);                      // 128 ints
  unsigned short* Wp = (unsigned short*)(ws + 786944);   // H*D bf16 packed
  unsigned short* Bp = (unsigned short*)(ws + 1311232);  // B*S*D bf16 frag-major

  k_prep<<<320, 256, 0, stream>>>((const unsigned int*)mask, flags, W_ctx, Wp,
                                  x, W_in, b_in, b_ctx, inp_pb);
  k_packctx<<<32768, 256, 0, stream>>>(context, Bp);
  k_att<<<dim3(S_ / 64, B_), 512, 0, stream>>>(Bp, Wp, inp_pb, V, att);
  k_softmax<<<B_, 256, 0, stream>>>(att, mask, flags, out_alpha);
  k_ypart16f<<<dim3(16, B_), 256, 0, stream>>>(Bp, out_alpha, y);
  k_hidden<<<B_, 256, 0, stream>>>(y, W_ctx, b_ctx, out_hidden);
}

// Round 17
// 182.719 us; speedup vs baseline: 1.5523x; 1.5523x over previous
//
#include <hip/hip_runtime.h>
#include <hip/hip_bf16.h>
#include <cstdint>

#define B_ 64
#define S_ 2048
#define D_ 512
#define H_ 512

typedef short s16x8 __attribute__((ext_vector_type(8)));
typedef float f32x4 __attribute__((ext_vector_type(4)));

static __device__ __forceinline__ unsigned short f2bf(float f) {
  __bf16 h = (__bf16)f;
  return __builtin_bit_cast(unsigned short, h);
}

// ---------------- fused prep: detect (128) + W-pack (128) + inp (256 blk) ----
__global__ __launch_bounds__(256) void k_prep(
    const unsigned int* __restrict__ mw, int* __restrict__ flags,
    const float* __restrict__ W, unsigned short* __restrict__ Wp,
    const float* __restrict__ x, const float* __restrict__ W_in,
    const float* __restrict__ b_in, const float* __restrict__ b_ctx,
    float* __restrict__ inp_pb) {
  const int bx = blockIdx.x;
  const int t = threadIdx.x;
  if (bx < 128) {
    __shared__ int blk;
    if (t == 0) blk = 0;
    __syncthreads();
    unsigned w = mw[bx * 256 + t];
    int bits = 0;
    if (w == 0x3F800000u) bits = 2;
    else if (w > 1u) bits = 1;
    unsigned long long a1 = __ballot(bits & 1);
    unsigned long long a2 = __ballot(bits & 2);
    if ((t & 63) == 0) {
      int v = (a1 ? 1 : 0) | (a2 ? 2 : 0);
      if (v) atomicOr(&blk, v);
    }
    __syncthreads();
    if (t == 0) flags[bx] = blk;
  } else if (bx < 256) {
    // pack W_ctx -> fragment-major bf16:
    // Wp[((kb*32+hb)*64+lane)*8+e] = bf16(W[hb*16+(lane&15)][kb*32+(lane>>4)*8+e])
    const int tid = (bx - 128) * 256 + t;
    const int lane = tid & 63;
    const int hb = (tid >> 6) & 31;
    const int kb = tid >> 11;
    const int h = hb * 16 + (lane & 15);
    const int k = kb * 32 + (lane >> 4) * 8;
    const float* src = W + (size_t)h * D_ + k;
    float4 a = *(const float4*)src;
    float4 c = *(const float4*)(src + 4);
    s16x8 o;
    o[0] = (short)f2bf(a.x); o[1] = (short)f2bf(a.y);
    o[2] = (short)f2bf(a.z); o[3] = (short)f2bf(a.w);
    o[4] = (short)f2bf(c.x); o[5] = (short)f2bf(c.y);
    o[6] = (short)f2bf(c.z); o[7] = (short)f2bf(c.w);
    *(s16x8*)(Wp + (size_t)tid * 8) = o;
  } else {
    // inp' = x @ W_in^T + b_in + b_ctx : 256 blocks = (b, h-quarter)
    const int bb = bx - 256;
    const int b = bb >> 2, hq = bb & 3;
    __shared__ float xs[D_];
    xs[t] = x[b * D_ + t];
    xs[t + 256] = x[b * D_ + t + 256];
    __syncthreads();
    const int h = hq * 128 + (t >> 1);
    const int half = t & 1;
    const float4* wr = (const float4*)(W_in + (size_t)h * D_) + half * 64;
    const float* xh = xs + half * 256;
    float acc = 0.f;
#pragma unroll 4
    for (int d4 = 0; d4 < 64; ++d4) {
      float4 w = wr[d4];
      acc += w.x * xh[d4 * 4] + w.y * xh[d4 * 4 + 1] + w.z * xh[d4 * 4 + 2] +
             w.w * xh[d4 * 4 + 3];
    }
    acc += __shfl_xor(acc, 1, 64);
    if (half == 0) inp_pb[b * H_ + h] = acc + b_in[h] + b_ctx[h];
  }
}

// ---------------- att[b,s] = sum_h V[h]*tanh(inp'[b,h] + (W_ctx@ctx^T)[h,s]) ----
// R13 schedule (measured best): depth-3 B staging (3 reg sets, tile t+3 issued
// at iter t), per-iter order ds_reads -> A-loads -> stage -> MFMA -> cvt_write,
// lgkm-only barriers (no vmcnt drain), 0-conflict 16B XOR swizzle, setprio
// around MFMA cluster. Epilogue tanh simplified: 1 - 2*rcp(e^{2x}+1)
// (limit-exact at +-inf; no abs/copysign/clamp).
__global__ __launch_bounds__(512, 2) void k_att(
    const float* __restrict__ context, const unsigned short* __restrict__ Wp,
    const float* __restrict__ inp_pb, const float* __restrict__ V,
    float* __restrict__ att) {
  __shared__ char bt[2][8192];  // [s 64][k 64] bf16, 128B rows, swizzled
  __shared__ float red[8][64];
  const int tid = threadIdx.x;
  const int wave = tid >> 6, lane = tid & 63;
  const int b = blockIdx.y, s0 = blockIdx.x * 64;
  const float* ctxb = context + ((size_t)b * S_ + s0) * D_;
  const int hbase = wave * 64;
  const int bln = lane & 15, blh = lane >> 4;

  const int srow = tid >> 3, kc8 = (tid & 7) * 8;
  const int sbyte = srow * 128 + ((kc8 * 2) ^ ((srow & 7) << 4));
  const float* gsrc = ctxb + (size_t)srow * D_ + kc8;

  const unsigned short* ap = Wp + ((size_t)(wave * 4) * 64 + lane) * 8;

  f32x4 acc[4][4];
#pragma unroll
  for (int m = 0; m < 4; ++m)
#pragma unroll
    for (int n = 0; n < 4; ++n) acc[m][n] = f32x4{0.f, 0.f, 0.f, 0.f};

  // depth-3 staging register sets: set i holds tile x with x%3 == i
  f32x4 sg0a, sg0b, sg1a, sg1b, sg2a, sg2b;
#define LOAD_SET0(T) { sg0a = __builtin_nontemporal_load((const f32x4*)(gsrc + (T)*64)); \
                       sg0b = __builtin_nontemporal_load((const f32x4*)(gsrc + (T)*64 + 4)); }
#define LOAD_SET1(T) { sg1a = __builtin_nontemporal_load((const f32x4*)(gsrc + (T)*64)); \
                       sg1b = __builtin_nontemporal_load((const f32x4*)(gsrc + (T)*64 + 4)); }
#define LOAD_SET2(T) { sg2a = __builtin_nontemporal_load((const f32x4*)(gsrc + (T)*64)); \
                       sg2b = __builtin_nontemporal_load((const f32x4*)(gsrc + (T)*64 + 4)); }
#define CVT_SET(A, Bv, BUF) { s16x8 hb_; \
    hb_[0] = (short)f2bf((A)[0]); hb_[1] = (short)f2bf((A)[1]); \
    hb_[2] = (short)f2bf((A)[2]); hb_[3] = (short)f2bf((A)[3]); \
    hb_[4] = (short)f2bf((Bv)[0]); hb_[5] = (short)f2bf((Bv)[1]); \
    hb_[6] = (short)f2bf((Bv)[2]); hb_[7] = (short)f2bf((Bv)[3]); \
    *(s16x8*)(&bt[BUF][sbyte]) = hb_; }

  // prologue: tiles 0,1,2 in flight; tile 0 written to bt[0]
  LOAD_SET0(0);
  LOAD_SET1(1);
  LOAD_SET2(2);
  CVT_SET(sg0a, sg0b, 0);
  asm volatile("s_waitcnt lgkmcnt(0)" ::: "memory");
  __builtin_amdgcn_s_barrier();
  __builtin_amdgcn_sched_barrier(0);

#pragma unroll
  for (int t = 0; t < 8; ++t) {
    const char* cur = bt[t & 1];
    // (1) ds_reads for both kk halves first (LDS latency starts ticking)
    s16x8 bfrag[2][4];
#pragma unroll
    for (int kk = 0; kk < 2; ++kk)
#pragma unroll
      for (int n = 0; n < 4; ++n) {
        const int sr = n * 16 + bln;
        const int off = (kk * 64 + blh * 16) ^ ((sr & 7) << 4);
        bfrag[kk][n] = *(const s16x8*)(cur + sr * 128 + off);
      }
    // (2) A-frag loads (8 contiguous 1KB bursts from L2; latency overlaps ds)
    s16x8 af[2][4];
#pragma unroll
    for (int kk = 0; kk < 2; ++kk)
#pragma unroll
      for (int m = 0; m < 4; ++m)
        af[kk][m] = *(const s16x8*)(ap + (size_t)(t * 2 + kk) * 32 * 512 +
                                    (size_t)m * 512);
    // (3) stage-load tile t+3 into set (t+3)%3 (in flight across barriers)
    if (t < 5) {
      const int s3 = (t + 3) % 3;
      if (s3 == 0) LOAD_SET0(t + 3)
      else if (s3 == 1) LOAD_SET1(t + 3)
      else LOAD_SET2(t + 3)
    }
    // (4) all 32 MFMAs, priority-boosted
    __builtin_amdgcn_s_setprio(1);
#pragma unroll
    for (int kk = 0; kk < 2; ++kk)
#pragma unroll
      for (int m = 0; m < 4; ++m)
#pragma unroll
        for (int n = 0; n < 4; ++n)
          acc[m][n] = __builtin_amdgcn_mfma_f32_16x16x32_bf16(af[kk][m],
                                                              bfrag[kk][n],
                                                              acc[m][n], 0, 0, 0);
    __builtin_amdgcn_s_setprio(0);
    // (5) write tile t+1 (loaded at iter t-2: ~2.7 iters of cover)
    if (t < 7) {
      const int s1 = (t + 1) % 3;
      const int nb = (t + 1) & 1;
      if (s1 == 0) CVT_SET(sg0a, sg0b, nb)
      else if (s1 == 1) CVT_SET(sg1a, sg1b, nb)
      else CVT_SET(sg2a, sg2b, nb)
    }
    // (6) barrier WITHOUT vmcnt drain
    asm volatile("s_waitcnt lgkmcnt(0)" ::: "memory");
    __builtin_amdgcn_s_barrier();
    __builtin_amdgcn_sched_barrier(0);
  }
#undef LOAD_SET0
#undef LOAD_SET1
#undef LOAD_SET2
#undef CVT_SET

  // epilogue: tanh + V-dot, reduce over h
  float attp[4] = {0.f, 0.f, 0.f, 0.f};
  const float* ib = inp_pb + b * H_;
#pragma unroll
  for (int m = 0; m < 4; ++m) {
#pragma unroll
    for (int j = 0; j < 4; ++j) {
      int h = hbase + m * 16 + (blh << 2) + j;
      float c = ib[h];
      float vh = V[h];
#pragma unroll
      for (int n = 0; n < 4; ++n) {
        float x = acc[m][n][j] + c;
        float e = __expf(2.f * x);
        float tt = 1.f - 2.f * __builtin_amdgcn_rcpf(e + 1.f);
        attp[n] += vh * tt;
      }
    }
  }
#pragma unroll
  for (int n = 0; n < 4; ++n) {
    attp[n] += __shfl_xor(attp[n], 16, 64);
    attp[n] += __shfl_xor(attp[n], 32, 64);
  }
  if (lane < 16) {
#pragma unroll
    for (int n = 0; n < 4; ++n) red[wave][n * 16 + lane] = attp[n];
  }
  __syncthreads();
  if (tid < 64) {
    float s = 0.f;
#pragma unroll
    for (int w = 0; w < 8; ++w) s += red[w][tid];
    att[(size_t)b * S_ + s0 + tid] = s;
  }
}

// ---------------- masked softmax over S -> alpha ----------------
__global__ void k_softmax(const float* __restrict__ att, const void* __restrict__ mask,
                          const int* __restrict__ flags, float* __restrict__ alpha) {
  const int b = blockIdx.x, t = threadIdx.x;
  __shared__ int cshared;
  __shared__ float sm[4];
  if (t < 64) {
    int v = flags[t] | flags[t + 64];
    for (int off = 32; off; off >>= 1) v |= __shfl_xor(v, off, 64);
    if (t == 0) cshared = v;
  }
  __syncthreads();
  const int c = cshared;
  const int mtype = (c & 2) ? 2 : (c & 1);  // 2=float, 1=bytes, 0=int32
  const unsigned char* m8 = (const unsigned char*)mask;
  const int* m32 = (const int*)mask;
  const float* mf = (const float*)mask;
  float vals[8];
  float mx = -3.0e38f;
#pragma unroll
  for (int i = 0; i < 8; ++i) {
    int s = t + i * 256;
    size_t idx = (size_t)b * S_ + s;
    int msk = (mtype == 1) ? (int)m8[idx] : (mtype == 2) ? (mf[idx] != 0.f) : m32[idx];
    float v = msk ? -__builtin_inff() : att[idx];
    vals[i] = v;
    mx = fmaxf(mx, v);
  }
  for (int off = 32; off; off >>= 1) mx = fmaxf(mx, __shfl_xor(mx, off, 64));
  if ((t & 63) == 0) sm[t >> 6] = mx;
  __syncthreads();
  mx = fmaxf(fmaxf(sm[0], sm[1]), fmaxf(sm[2], sm[3]));
  float es[8];
  float sum = 0.f;
#pragma unroll
  for (int i = 0; i < 8; ++i) {
    es[i] = __expf(vals[i] - mx);
    sum += es[i];
  }
  for (int off = 32; off; off >>= 1) sum += __shfl_xor(sum, off, 64);
  __syncthreads();
  if ((t & 63) == 0) sm[t >> 6] = sum;
  __syncthreads();
  sum = sm[0] + sm[1] + sm[2] + sm[3];
  float inv = __fdividef(1.f, sum);
#pragma unroll
  for (int i = 0; i < 8; ++i) alpha[(size_t)b * S_ + t + i * 256] = es[i] * inv;
}

// ---------------- y partials: y[b,d] = sum_s alpha*context (f32) ----------------
__global__ void k_ypart(const float* __restrict__ context,
                        const float* __restrict__ alpha, float* __restrict__ y_part) {
  const int chunk = blockIdx.x, b = blockIdx.y, t = threadIdx.x;
  __shared__ float al[256];
  __shared__ float4 part[128];
  al[t] = alpha[(size_t)b * S_ + chunk * 256 + t];
  __syncthreads();
  const int d4 = t & 127, sr = t >> 7;
  const float4* base = (const float4*)(context + ((size_t)b * S_ + chunk * 256) * D_);
  float4 acc = make_float4(0.f, 0.f, 0.f, 0.f);
  for (int i = 0; i < 128; ++i) {
    int s = sr + 2 * i;
    float4 v = base[(size_t)s * 128 + d4];
    float a = al[s];
    acc.x += a * v.x; acc.y += a * v.y; acc.z += a * v.z; acc.w += a * v.w;
  }
  if (sr == 1) part[d4] = acc;
  __syncthreads();
  if (sr == 0) {
    float4 o = part[d4];
    o.x += acc.x; o.y += acc.y; o.z += acc.z; o.w += acc.w;
    *(float4*)(y_part + ((size_t)(b * 8 + chunk)) * D_ + d4 * 4) = o;
  }
}

// ---------------- hidden = W_ctx @ y + b_ctx : 256 blocks = (b, h-quarter) ----
__global__ __launch_bounds__(256) void k_hidden(
    const float* __restrict__ y_part, const float* __restrict__ W_ctx,
    const float* __restrict__ b_ctx, float* __restrict__ hidden) {
  const int bx = blockIdx.x;
  const int b = bx >> 2, hq = bx & 3;
  const int t = threadIdx.x;
  __shared__ float ys[D_];
  for (int d = t; d < D_; d += 256) {
    float s = 0.f;
#pragma unroll
    for (int c = 0; c < 8; ++c) s += y_part[((size_t)(b * 8 + c)) * D_ + d];
    ys[d] = s;
  }
  __syncthreads();
  const int h = hq * 128 + (t >> 1);
  const int half = t & 1;
  const float4* wr = (const float4*)(W_ctx + (size_t)h * D_) + half * 64;
  const float* yh = ys + half * 256;
  float acc = 0.f;
#pragma unroll 4
  for (int d4 = 0; d4 < 64; ++d4) {
    float4 w = wr[d4];
    acc += w.x * yh[d4 * 4] + w.y * yh[d4 * 4 + 1] + w.z * yh[d4 * 4 + 2] +
           w.w * yh[d4 * 4 + 3];
  }
  acc += __shfl_xor(acc, 1, 64);
  if (half == 0) hidden[b * H_ + h] = acc + b_ctx[h];
}

extern "C" void kernel_launch(void* const* d_in, const int* in_sizes, int n_in,
                              void* d_out, int out_size, void* d_ws, size_t ws_size,
                              hipStream_t stream) {
  (void)in_sizes; (void)n_in; (void)out_size; (void)ws_size;
  const float* x = (const float*)d_in[0];
  const float* context = (const float*)d_in[1];
  const void* mask = d_in[2];
  const float* W_in = (const float*)d_in[3];
  const float* b_in = (const float*)d_in[4];
  const float* W_ctx = (const float*)d_in[5];
  const float* b_ctx = (const float*)d_in[6];
  const float* V = (const float*)d_in[7];

  float* out_hidden = (float*)d_out;           // [B,H]
  float* out_alpha = (float*)d_out + B_ * H_;  // [B,S]

  // workspace: inp_pb 128K | att 512K | y_part 1M | flags 512B | Wp 512K
  char* ws = (char*)d_ws;
  float* inp_pb = (float*)ws;                            // B*H f32
  float* att = (float*)(ws + 131072);                    // B*S f32
  float* y_part = (float*)(ws + 655360);                 // B*8*D f32
  int* flags = (int*)(ws + 1703936);                     // 128 ints
  unsigned short* Wp = (unsigned short*)(ws + 1704448);  // H*D bf16 packed

  k_prep<<<512, 256, 0, stream>>>((const unsigned int*)mask, flags, W_ctx, Wp,
                                  x, W_in, b_in, b_ctx, inp_pb);
  k_att<<<dim3(S_ / 64, B_), 512, 0, stream>>>(context, Wp, inp_pb, V, att);
  k_softmax<<<B_, 256, 0, stream>>>(att, mask, flags, out_alpha);
  k_ypart<<<dim3(8, B_), 256, 0, stream>>>(context, out_alpha, y_part);
  k_hidden<<<256, 256, 0, stream>>>(y_part, W_ctx, b_ctx, out_hidden);
}

// Round 18
// 182.507 us; speedup vs baseline: 1.5541x; 1.0012x over previous
//
#include <hip/hip_runtime.h>
#include <hip/hip_bf16.h>
#include <cstdint>

#define B_ 64
#define S_ 2048
#define D_ 512
#define H_ 512

typedef short s16x8 __attribute__((ext_vector_type(8)));
typedef float f32x4 __attribute__((ext_vector_type(4)));

static __device__ __forceinline__ unsigned short f2bf(float f) {
  __bf16 h = (__bf16)f;
  return __builtin_bit_cast(unsigned short, h);
}

// ---------------- fused prep: detect (128) + W-pack (128) + inp (256 blk) ----
__global__ __launch_bounds__(256) void k_prep(
    const unsigned int* __restrict__ mw, int* __restrict__ flags,
    const float* __restrict__ W, unsigned short* __restrict__ Wp,
    const float* __restrict__ x, const float* __restrict__ W_in,
    const float* __restrict__ b_in, const float* __restrict__ b_ctx,
    float* __restrict__ inp_pb) {
  const int bx = blockIdx.x;
  const int t = threadIdx.x;
  if (bx < 128) {
    __shared__ int blk;
    if (t == 0) blk = 0;
    __syncthreads();
    unsigned w = mw[bx * 256 + t];
    int bits = 0;
    if (w == 0x3F800000u) bits = 2;
    else if (w > 1u) bits = 1;
    unsigned long long a1 = __ballot(bits & 1);
    unsigned long long a2 = __ballot(bits & 2);
    if ((t & 63) == 0) {
      int v = (a1 ? 1 : 0) | (a2 ? 2 : 0);
      if (v) atomicOr(&blk, v);
    }
    __syncthreads();
    if (t == 0) flags[bx] = blk;
  } else if (bx < 256) {
    // pack W_ctx -> fragment-major bf16:
    // Wp[((kb*32+hb)*64+lane)*8+e] = bf16(W[hb*16+(lane&15)][kb*32+(lane>>4)*8+e])
    const int tid = (bx - 128) * 256 + t;
    const int lane = tid & 63;
    const int hb = (tid >> 6) & 31;
    const int kb = tid >> 11;
    const int h = hb * 16 + (lane & 15);
    const int k = kb * 32 + (lane >> 4) * 8;
    const float* src = W + (size_t)h * D_ + k;
    float4 a = *(const float4*)src;
    float4 c = *(const float4*)(src + 4);
    s16x8 o;
    o[0] = (short)f2bf(a.x); o[1] = (short)f2bf(a.y);
    o[2] = (short)f2bf(a.z); o[3] = (short)f2bf(a.w);
    o[4] = (short)f2bf(c.x); o[5] = (short)f2bf(c.y);
    o[6] = (short)f2bf(c.z); o[7] = (short)f2bf(c.w);
    *(s16x8*)(Wp + (size_t)tid * 8) = o;
  } else {
    // inp' = x @ W_in^T + b_in + b_ctx : 256 blocks = (b, h-quarter)
    const int bb = bx - 256;
    const int b = bb >> 2, hq = bb & 3;
    __shared__ float xs[D_];
    xs[t] = x[b * D_ + t];
    xs[t + 256] = x[b * D_ + t + 256];
    __syncthreads();
    const int h = hq * 128 + (t >> 1);
    const int half = t & 1;
    const float4* wr = (const float4*)(W_in + (size_t)h * D_) + half * 64;
    const float* xh = xs + half * 256;
    float acc = 0.f;
#pragma unroll 4
    for (int d4 = 0; d4 < 64; ++d4) {
      float4 w = wr[d4];
      acc += w.x * xh[d4 * 4] + w.y * xh[d4 * 4 + 1] + w.z * xh[d4 * 4 + 2] +
             w.w * xh[d4 * 4 + 3];
    }
    acc += __shfl_xor(acc, 1, 64);
    if (half == 0) inp_pb[b * H_ + h] = acc + b_in[h] + b_ctx[h];
  }
}

// ---------------- att[b,s] = sum_h V[h]*tanh(inp'[b,h] + (W_ctx@ctx^T)[h,s]) ----
// R13 schedule (measured best): depth-3 B staging, ds->A->stage->MFMA order,
// lgkm-only barriers, 0-conflict swizzle, setprio, cheap limit-exact tanh.
__global__ __launch_bounds__(512, 2) void k_att(
    const float* __restrict__ context, const unsigned short* __restrict__ Wp,
    const float* __restrict__ inp_pb, const float* __restrict__ V,
    float* __restrict__ att) {
  __shared__ char bt[2][8192];  // [s 64][k 64] bf16, 128B rows, swizzled
  __shared__ float red[8][64];
  const int tid = threadIdx.x;
  const int wave = tid >> 6, lane = tid & 63;
  const int b = blockIdx.y, s0 = blockIdx.x * 64;
  const float* ctxb = context + ((size_t)b * S_ + s0) * D_;
  const int hbase = wave * 64;
  const int bln = lane & 15, blh = lane >> 4;

  const int srow = tid >> 3, kc8 = (tid & 7) * 8;
  const int sbyte = srow * 128 + ((kc8 * 2) ^ ((srow & 7) << 4));
  const float* gsrc = ctxb + (size_t)srow * D_ + kc8;

  const unsigned short* ap = Wp + ((size_t)(wave * 4) * 64 + lane) * 8;

  f32x4 acc[4][4];
#pragma unroll
  for (int m = 0; m < 4; ++m)
#pragma unroll
    for (int n = 0; n < 4; ++n) acc[m][n] = f32x4{0.f, 0.f, 0.f, 0.f};

  // depth-3 staging register sets: set i holds tile x with x%3 == i
  f32x4 sg0a, sg0b, sg1a, sg1b, sg2a, sg2b;
#define LOAD_SET0(T) { sg0a = __builtin_nontemporal_load((const f32x4*)(gsrc + (T)*64)); \
                       sg0b = __builtin_nontemporal_load((const f32x4*)(gsrc + (T)*64 + 4)); }
#define LOAD_SET1(T) { sg1a = __builtin_nontemporal_load((const f32x4*)(gsrc + (T)*64)); \
                       sg1b = __builtin_nontemporal_load((const f32x4*)(gsrc + (T)*64 + 4)); }
#define LOAD_SET2(T) { sg2a = __builtin_nontemporal_load((const f32x4*)(gsrc + (T)*64)); \
                       sg2b = __builtin_nontemporal_load((const f32x4*)(gsrc + (T)*64 + 4)); }
#define CVT_SET(A, Bv, BUF) { s16x8 hb_; \
    hb_[0] = (short)f2bf((A)[0]); hb_[1] = (short)f2bf((A)[1]); \
    hb_[2] = (short)f2bf((A)[2]); hb_[3] = (short)f2bf((A)[3]); \
    hb_[4] = (short)f2bf((Bv)[0]); hb_[5] = (short)f2bf((Bv)[1]); \
    hb_[6] = (short)f2bf((Bv)[2]); hb_[7] = (short)f2bf((Bv)[3]); \
    *(s16x8*)(&bt[BUF][sbyte]) = hb_; }

  // prologue: tiles 0,1,2 in flight; tile 0 written to bt[0]
  LOAD_SET0(0);
  LOAD_SET1(1);
  LOAD_SET2(2);
  CVT_SET(sg0a, sg0b, 0);
  asm volatile("s_waitcnt lgkmcnt(0)" ::: "memory");
  __builtin_amdgcn_s_barrier();
  __builtin_amdgcn_sched_barrier(0);

#pragma unroll
  for (int t = 0; t < 8; ++t) {
    const char* cur = bt[t & 1];
    // (1) ds_reads for both kk halves first (LDS latency starts ticking)
    s16x8 bfrag[2][4];
#pragma unroll
    for (int kk = 0; kk < 2; ++kk)
#pragma unroll
      for (int n = 0; n < 4; ++n) {
        const int sr = n * 16 + bln;
        const int off = (kk * 64 + blh * 16) ^ ((sr & 7) << 4);
        bfrag[kk][n] = *(const s16x8*)(cur + sr * 128 + off);
      }
    // (2) A-frag loads (8 contiguous 1KB bursts from L2; latency overlaps ds)
    s16x8 af[2][4];
#pragma unroll
    for (int kk = 0; kk < 2; ++kk)
#pragma unroll
      for (int m = 0; m < 4; ++m)
        af[kk][m] = *(const s16x8*)(ap + (size_t)(t * 2 + kk) * 32 * 512 +
                                    (size_t)m * 512);
    // (3) stage-load tile t+3 into set (t+3)%3 (in flight across barriers)
    if (t < 5) {
      const int s3 = (t + 3) % 3;
      if (s3 == 0) LOAD_SET0(t + 3)
      else if (s3 == 1) LOAD_SET1(t + 3)
      else LOAD_SET2(t + 3)
    }
    // (4) all 32 MFMAs, priority-boosted
    __builtin_amdgcn_s_setprio(1);
#pragma unroll
    for (int kk = 0; kk < 2; ++kk)
#pragma unroll
      for (int m = 0; m < 4; ++m)
#pragma unroll
        for (int n = 0; n < 4; ++n)
          acc[m][n] = __builtin_amdgcn_mfma_f32_16x16x32_bf16(af[kk][m],
                                                              bfrag[kk][n],
                                                              acc[m][n], 0, 0, 0);
    __builtin_amdgcn_s_setprio(0);
    // (5) write tile t+1 (loaded at iter t-2: ~2.7 iters of cover)
    if (t < 7) {
      const int s1 = (t + 1) % 3;
      const int nb = (t + 1) & 1;
      if (s1 == 0) CVT_SET(sg0a, sg0b, nb)
      else if (s1 == 1) CVT_SET(sg1a, sg1b, nb)
      else CVT_SET(sg2a, sg2b, nb)
    }
    // (6) barrier WITHOUT vmcnt drain
    asm volatile("s_waitcnt lgkmcnt(0)" ::: "memory");
    __builtin_amdgcn_s_barrier();
    __builtin_amdgcn_sched_barrier(0);
  }
#undef LOAD_SET0
#undef LOAD_SET1
#undef LOAD_SET2
#undef CVT_SET

  // epilogue: tanh + V-dot, reduce over h
  float attp[4] = {0.f, 0.f, 0.f, 0.f};
  const float* ib = inp_pb + b * H_;
#pragma unroll
  for (int m = 0; m < 4; ++m) {
#pragma unroll
    for (int j = 0; j < 4; ++j) {
      int h = hbase + m * 16 + (blh << 2) + j;
      float c = ib[h];
      float vh = V[h];
#pragma unroll
      for (int n = 0; n < 4; ++n) {
        float x = acc[m][n][j] + c;
        float e = __expf(2.f * x);
        float tt = 1.f - 2.f * __builtin_amdgcn_rcpf(e + 1.f);
        attp[n] += vh * tt;
      }
    }
  }
#pragma unroll
  for (int n = 0; n < 4; ++n) {
    attp[n] += __shfl_xor(attp[n], 16, 64);
    attp[n] += __shfl_xor(attp[n], 32, 64);
  }
  if (lane < 16) {
#pragma unroll
    for (int n = 0; n < 4; ++n) red[wave][n * 16 + lane] = attp[n];
  }
  __syncthreads();
  if (tid < 64) {
    float s = 0.f;
#pragma unroll
    for (int w = 0; w < 8; ++w) s += red[w][tid];
    att[(size_t)b * S_ + s0 + tid] = s;
  }
}

// ---------------- masked softmax over S -> alpha ----------------
__global__ void k_softmax(const float* __restrict__ att, const void* __restrict__ mask,
                          const int* __restrict__ flags, float* __restrict__ alpha) {
  const int b = blockIdx.x, t = threadIdx.x;
  __shared__ int cshared;
  __shared__ float sm[4];
  if (t < 64) {
    int v = flags[t] | flags[t + 64];
    for (int off = 32; off; off >>= 1) v |= __shfl_xor(v, off, 64);
    if (t == 0) cshared = v;
  }
  __syncthreads();
  const int c = cshared;
  const int mtype = (c & 2) ? 2 : (c & 1);  // 2=float, 1=bytes, 0=int32
  const unsigned char* m8 = (const unsigned char*)mask;
  const int* m32 = (const int*)mask;
  const float* mf = (const float*)mask;
  float vals[8];
  float mx = -3.0e38f;
#pragma unroll
  for (int i = 0; i < 8; ++i) {
    int s = t + i * 256;
    size_t idx = (size_t)b * S_ + s;
    int msk = (mtype == 1) ? (int)m8[idx] : (mtype == 2) ? (mf[idx] != 0.f) : m32[idx];
    float v = msk ? -__builtin_inff() : att[idx];
    vals[i] = v;
    mx = fmaxf(mx, v);
  }
  for (int off = 32; off; off >>= 1) mx = fmaxf(mx, __shfl_xor(mx, off, 64));
  if ((t & 63) == 0) sm[t >> 6] = mx;
  __syncthreads();
  mx = fmaxf(fmaxf(sm[0], sm[1]), fmaxf(sm[2], sm[3]));
  float es[8];
  float sum = 0.f;
#pragma unroll
  for (int i = 0; i < 8; ++i) {
    es[i] = __expf(vals[i] - mx);
    sum += es[i];
  }
  for (int off = 32; off; off >>= 1) sum += __shfl_xor(sum, off, 64);
  __syncthreads();
  if ((t & 63) == 0) sm[t >> 6] = sum;
  __syncthreads();
  sum = sm[0] + sm[1] + sm[2] + sm[3];
  float inv = __fdividef(1.f, sum);
#pragma unroll
  for (int i = 0; i < 8; ++i) alpha[(size_t)b * S_ + t + i * 256] = es[i] * inv;
}

// ---------------- y partials: y[b,d] = sum_s alpha*context (f32) ----------------
// REVERSE-ORDER read (b,chunk descending): context (268MB) ~= L3 (256MB);
// k_att just streamed it ascending, so L3 holds the tail. Reading backwards
// touches hot lines first (Belady trick) -> mostly L3-served instead of HBM.
// Also leaves b~0 hot for the NEXT replay's k_att ascending read.
__global__ void k_ypart(const float* __restrict__ context,
                        const float* __restrict__ alpha, float* __restrict__ y_part) {
  const int chunk = 7 - blockIdx.x, b = 63 - blockIdx.y, t = threadIdx.x;
  __shared__ float al[256];
  __shared__ float4 part[128];
  al[t] = alpha[(size_t)b * S_ + chunk * 256 + t];
  __syncthreads();
  const int d4 = t & 127, sr = t >> 7;
  const float4* base = (const float4*)(context + ((size_t)b * S_ + chunk * 256) * D_);
  float4 acc = make_float4(0.f, 0.f, 0.f, 0.f);
  for (int i = 0; i < 128; ++i) {
    int s = sr + 2 * i;
    float4 v = base[(size_t)s * 128 + d4];
    float a = al[s];
    acc.x += a * v.x; acc.y += a * v.y; acc.z += a * v.z; acc.w += a * v.w;
  }
  if (sr == 1) part[d4] = acc;
  __syncthreads();
  if (sr == 0) {
    float4 o = part[d4];
    o.x += acc.x; o.y += acc.y; o.z += acc.z; o.w += acc.w;
    *(float4*)(y_part + ((size_t)(b * 8 + chunk)) * D_ + d4 * 4) = o;
  }
}

// ---------------- hidden = W_ctx @ y + b_ctx : 256 blocks = (b, h-quarter) ----
__global__ __launch_bounds__(256) void k_hidden(
    const float* __restrict__ y_part, const float* __restrict__ W_ctx,
    const float* __restrict__ b_ctx, float* __restrict__ hidden) {
  const int bx = blockIdx.x;
  const int b = bx >> 2, hq = bx & 3;
  const int t = threadIdx.x;
  __shared__ float ys[D_];
  for (int d = t; d < D_; d += 256) {
    float s = 0.f;
#pragma unroll
    for (int c = 0; c < 8; ++c) s += y_part[((size_t)(b * 8 + c)) * D_ + d];
    ys[d] = s;
  }
  __syncthreads();
  const int h = hq * 128 + (t >> 1);
  const int half = t & 1;
  const float4* wr = (const float4*)(W_ctx + (size_t)h * D_) + half * 64;
  const float* yh = ys + half * 256;
  float acc = 0.f;
#pragma unroll 4
  for (int d4 = 0; d4 < 64; ++d4) {
    float4 w = wr[d4];
    acc += w.x * yh[d4 * 4] + w.y * yh[d4 * 4 + 1] + w.z * yh[d4 * 4 + 2] +
           w.w * yh[d4 * 4 + 3];
  }
  acc += __shfl_xor(acc, 1, 64);
  if (half == 0) hidden[b * H_ + h] = acc + b_ctx[h];
}

extern "C" void kernel_launch(void* const* d_in, const int* in_sizes, int n_in,
                              void* d_out, int out_size, void* d_ws, size_t ws_size,
                              hipStream_t stream) {
  (void)in_sizes; (void)n_in; (void)out_size; (void)ws_size;
  const float* x = (const float*)d_in[0];
  const float* context = (const float*)d_in[1];
  const void* mask = d_in[2];
  const float* W_in = (const float*)d_in[3];
  const float* b_in = (const float*)d_in[4];
  const float* W_ctx = (const float*)d_in[5];
  const float* b_ctx = (const float*)d_in[6];
  const float* V = (const float*)d_in[7];

  float* out_hidden = (float*)d_out;           // [B,H]
  float* out_alpha = (float*)d_out + B_ * H_;  // [B,S]

  // workspace: inp_pb 128K | att 512K | y_part 1M | flags 512B | Wp 512K
  char* ws = (char*)d_ws;
  float* inp_pb = (float*)ws;                            // B*H f32
  float* att = (float*)(ws + 131072);                    // B*S f32
  float* y_part = (float*)(ws + 655360);                 // B*8*D f32
  int* flags = (int*)(ws + 1703936);                     // 128 ints
  unsigned short* Wp = (unsigned short*)(ws + 1704448);  // H*D bf16 packed

  k_prep<<<512, 256, 0, stream>>>((const unsigned int*)mask, flags, W_ctx, Wp,
                                  x, W_in, b_in, b_ctx, inp_pb);
  k_att<<<dim3(S_ / 64, B_), 512, 0, stream>>>(context, Wp, inp_pb, V, att);
  k_softmax<<<B_, 256, 0, stream>>>(att, mask, flags, out_alpha);
  k_ypart<<<dim3(8, B_), 256, 0, stream>>>(context, out_alpha, y_part);
  k_hidden<<<256, 256, 0, stream>>>(y_part, W_ctx, b_ctx, out_hidden);
}